// Round 1
// baseline (1578.721 us; speedup 1.0000x reference)
//
#include <hip/hip_runtime.h>

#define GLOBAL_AS __attribute__((address_space(1)))
#define LDS_AS    __attribute__((address_space(3)))

typedef __bf16 bf16x8 __attribute__((ext_vector_type(8)));
typedef float  floatx4 __attribute__((ext_vector_type(4)));

static constexpr int M_BATCH = 4096;
static constexpr int NPTS    = 512;
static constexpr int EMB     = 2048;
static constexpr int F0      = 1023;     // 2*NPTS-1
static constexpr int F0P     = 1024;     // padded feature count, K multiple of 64
static constexpr int K0      = 9 * F0P;  // 9216
static constexpr int K12     = 9 * EMB;  // 18432

// ---- float -> bf16 round-to-nearest-even ----
__device__ __forceinline__ unsigned short f2bf(float f) {
    unsigned int u = __float_as_uint(f);
    u += 0x7fffu + ((u >> 16) & 1u);
    return (unsigned short)(u >> 16);
}

// ---- relu + 8 cubic B-spline bases, exactly mirroring the reference recursion ----
__device__ __forceinline__ void kan_phi(float x, float* v) {
    float g[12];
    #pragma unroll
    for (int i = 0; i < 12; ++i) g[i] = (float)(i - 3) * 0.4f - 1.0f;
    float b[11];
    #pragma unroll
    for (int i = 0; i < 11; ++i) b[i] = (x >= g[i] && x < g[i + 1]) ? 1.0f : 0.0f;
    #pragma unroll
    for (int k = 1; k <= 3; ++k) {
        #pragma unroll
        for (int i = 0; i + k < 11; ++i) {
            float left  = (x - g[i]) / (g[i + k] - g[i]);
            float right = (g[i + k + 1] - x) / (g[i + k + 1] - g[i + 1]);
            b[i] = left * b[i] + right * b[i + 1];
        }
    }
    v[0] = x > 0.0f ? x : 0.0f;
    #pragma unroll
    for (int i = 0; i < 8; ++i) v[1 + i] = b[i];
}

// ---- build h0 (4096 x 1023): interleave xs[:, :-1], ys[:, :-1], then xs[:, -1] ----
__global__ void build_h0_kernel(const float* __restrict__ xs,
                                const float* __restrict__ ys,
                                float* __restrict__ h0) {
    int idx = blockIdx.x * blockDim.x + threadIdx.x;
    if (idx >= M_BATCH * F0) return;
    int n = idx / F0, c = idx - n * F0;
    float v;
    if (c == F0 - 1) v = xs[n * NPTS + NPTS - 1];
    else {
        int i = c >> 1;
        v = (c & 1) ? ys[n * NPTS + i] : xs[n * NPTS + i];
    }
    h0[idx] = v;
}

// ---- expand h (N x F fp32) -> Phi (N x 9*Fp bf16): [relu, B0..B7] per feature ----
__global__ void expand_kernel(const float* __restrict__ h,
                              unsigned short* __restrict__ phi,
                              int Nrows, int F, int Fp) {
    int idx = blockIdx.x * blockDim.x + threadIdx.x;
    if (idx >= Nrows * Fp) return;
    int n = idx / Fp, f = idx - n * Fp;
    unsigned short o[9];
    if (f < F) {
        float v[9];
        kan_phi(h[(size_t)n * F + f], v);
        #pragma unroll
        for (int i = 0; i < 9; ++i) o[i] = f2bf(v[i]);
    } else {
        #pragma unroll
        for (int i = 0; i < 9; ++i) o[i] = 0;
    }
    size_t off = (size_t)n * (size_t)(9 * Fp) + (size_t)f * 9;
    #pragma unroll
    for (int i = 0; i < 9; ++i) phi[off + i] = o[i];
}

// ---- pack W^T (O x 9*Fp bf16): slot 0 = base_w, slots 1..8 = spline_w * scaler ----
__global__ void pack_w_kernel(const float* __restrict__ bw,
                              const float* __restrict__ sw,
                              const float* __restrict__ sc,
                              unsigned short* __restrict__ wt,
                              int O, int F, int Fp) {
    int idx = blockIdx.x * blockDim.x + threadIdx.x;
    if (idx >= O * Fp) return;
    int o = idx / Fp, f = idx - o * Fp;
    size_t dst = (size_t)o * (size_t)(9 * Fp) + (size_t)f * 9;
    if (f < F) {
        size_t s = (size_t)o * F + f;
        float scale = sc[s];
        wt[dst] = f2bf(bw[s]);
        #pragma unroll
        for (int j = 0; j < 8; ++j)
            wt[dst + 1 + j] = f2bf(sw[s * 8 + j] * scale);
    } else {
        #pragma unroll
        for (int j = 0; j < 9; ++j) wt[dst + j] = 0;
    }
}

// ---- bf16 GEMM: C(MxN fp32) = A(MxK bf16, row-major) * B^T(NxK bf16, row-major) ----
// m97 structure: 128x128 tile, BK=64, global_load_lds width 16, XOR-swizzled LDS.
__global__ __launch_bounds__(256, 2)
void gemm_bt_kernel(const unsigned short* __restrict__ A,
                    const unsigned short* __restrict__ B,
                    float* __restrict__ C,
                    int M, int N, int K) {
    __shared__ __align__(16) unsigned short Alds[128 * 64];
    __shared__ __align__(16) unsigned short Blds[128 * 64];

    const int tid  = threadIdx.x;
    const int wave = tid >> 6;
    const int lane = tid & 63;
    const int bm = blockIdx.y;
    const int bn = blockIdx.x;
    const int wm = (wave >> 1) * 64;
    const int wn = (wave & 1) * 64;

    floatx4 zero = {0.f, 0.f, 0.f, 0.f};
    floatx4 acc[4][4];
    #pragma unroll
    for (int i = 0; i < 4; ++i)
        #pragma unroll
        for (int j = 0; j < 4; ++j)
            acc[i][j] = zero;

    // staging pattern: linear chunk q = row*8 + physChunk; logical chunk = phys ^ (row&7)
    int srow[4], scol[4];
    #pragma unroll
    for (int r = 0; r < 4; ++r) {
        int q = (r * 4 + wave) * 64 + lane;
        int row = q >> 3;
        int p = q & 7;
        srow[r] = row;
        scol[r] = (p ^ (row & 7)) * 8;   // element offset within the 64-wide k-tile
    }

    const unsigned short* Ab = A + (size_t)bm * 128 * K;
    const unsigned short* Bb = B + (size_t)bn * 128 * K;

    const int fr = lane & 15;   // m (or n) within 16x16 tile
    const int fq = lane >> 4;   // quad 0..3 -> k chunk

    for (int k0 = 0; k0 < K; k0 += 64) {
        #pragma unroll
        for (int r = 0; r < 4; ++r) {
            __builtin_amdgcn_global_load_lds(
                (const GLOBAL_AS void*)(Ab + (size_t)srow[r] * K + (k0 + scol[r])),
                (LDS_AS void*)(Alds + (r * 4 + wave) * 512),
                16, 0, 0);
        }
        #pragma unroll
        for (int r = 0; r < 4; ++r) {
            __builtin_amdgcn_global_load_lds(
                (const GLOBAL_AS void*)(Bb + (size_t)srow[r] * K + (k0 + scol[r])),
                (LDS_AS void*)(Blds + (r * 4 + wave) * 512),
                16, 0, 0);
        }
        __syncthreads();   // compiler emits s_waitcnt vmcnt(0) before s_barrier

        #pragma unroll
        for (int ks = 0; ks < 2; ++ks) {
            bf16x8 av[4], bv[4];
            #pragma unroll
            for (int mt = 0; mt < 4; ++mt) {
                int row = wm + mt * 16 + fr;
                int c   = ks * 4 + fq;
                int off = row * 64 + ((c ^ (row & 7)) * 8);
                av[mt] = *reinterpret_cast<const bf16x8*>(&Alds[off]);
            }
            #pragma unroll
            for (int nt = 0; nt < 4; ++nt) {
                int row = wn + nt * 16 + fr;
                int c   = ks * 4 + fq;
                int off = row * 64 + ((c ^ (row & 7)) * 8);
                bv[nt] = *reinterpret_cast<const bf16x8*>(&Blds[off]);
            }
            #pragma unroll
            for (int mt = 0; mt < 4; ++mt)
                #pragma unroll
                for (int nt = 0; nt < 4; ++nt)
                    acc[mt][nt] = __builtin_amdgcn_mfma_f32_16x16x32_bf16(
                        av[mt], bv[nt], acc[mt][nt], 0, 0, 0);
        }
        __syncthreads();
    }

    // epilogue: C/D layout col = lane&15, row = (lane>>4)*4 + reg  [m89 verified]
    const int rq = fq * 4;
    #pragma unroll
    for (int mt = 0; mt < 4; ++mt) {
        #pragma unroll
        for (int nt = 0; nt < 4; ++nt) {
            #pragma unroll
            for (int r = 0; r < 4; ++r) {
                int gr = bm * 128 + wm + mt * 16 + rq + r;
                int gc = bn * 128 + wn + nt * 16 + fr;
                C[(size_t)gr * N + gc] = acc[mt][nt][r];
            }
        }
    }
}

extern "C" void kernel_launch(void* const* d_in, const int* in_sizes, int n_in,
                              void* d_out, int out_size, void* d_ws, size_t ws_size,
                              hipStream_t stream) {
    const float* xs  = (const float*)d_in[0];
    const float* ys  = (const float*)d_in[1];
    const float* bw0 = (const float*)d_in[2];
    const float* sw0 = (const float*)d_in[3];
    const float* sc0 = (const float*)d_in[4];
    const float* bw1 = (const float*)d_in[5];
    const float* sw1 = (const float*)d_in[6];
    const float* sc1 = (const float*)d_in[7];
    const float* bw2 = (const float*)d_in[8];
    const float* sw2 = (const float*)d_in[9];
    const float* sc2 = (const float*)d_in[10];

    // workspace layout (bytes)
    char* ws = (char*)d_ws;
    unsigned short* Phi = (unsigned short*)ws;                         // 4096*18432*2 = 150,994,944
    unsigned short* Wt  = (unsigned short*)(ws + 150994944);           // 18432*2048*2 =  75,497,472
    float* h0 = (float*)(ws + 150994944 + 75497472);                   // 4096*1023*4  =  16,760,832
    float* h1 = (float*)((char*)h0 + 16760832);                        // 4096*2048*4  =  33,554,432
    float* h2 = (float*)((char*)h1 + 33554432);                        // 4096*2048*4  =  33,554,432
    (void)ws_size; (void)in_sizes; (void)n_in; (void)out_size;

    const int T = 256;

    // stage 0: input interleave
    build_h0_kernel<<<(M_BATCH * F0 + T - 1) / T, T, 0, stream>>>(xs, ys, h0);

    // ---- layer 0: 4096 x 9216 x 2048 ----
    pack_w_kernel<<<(EMB * F0P + T - 1) / T, T, 0, stream>>>(bw0, sw0, sc0, Wt, EMB, F0, F0P);
    expand_kernel<<<(M_BATCH * F0P + T - 1) / T, T, 0, stream>>>(h0, Phi, M_BATCH, F0, F0P);
    gemm_bt_kernel<<<dim3(EMB / 128, M_BATCH / 128), T, 0, stream>>>(Phi, Wt, h1, M_BATCH, EMB, K0);

    // ---- layer 1: 4096 x 18432 x 2048 ----
    pack_w_kernel<<<(EMB * EMB + T - 1) / T, T, 0, stream>>>(bw1, sw1, sc1, Wt, EMB, EMB, EMB);
    expand_kernel<<<(M_BATCH * EMB + T - 1) / T, T, 0, stream>>>(h1, Phi, M_BATCH, EMB, EMB);
    gemm_bt_kernel<<<dim3(EMB / 128, M_BATCH / 128), T, 0, stream>>>(Phi, Wt, h2, M_BATCH, EMB, K12);

    // ---- layer 2: 4096 x 18432 x 512 ----
    pack_w_kernel<<<(NPTS * EMB + T - 1) / T, T, 0, stream>>>(bw2, sw2, sc2, Wt, NPTS, EMB, EMB);
    expand_kernel<<<(M_BATCH * EMB + T - 1) / T, T, 0, stream>>>(h2, Phi, M_BATCH, EMB, EMB);
    gemm_bt_kernel<<<dim3(NPTS / 128, M_BATCH / 128), T, 0, stream>>>(Phi, Wt, (float*)d_out, M_BATCH, NPTS, K12);
}